// Round 11
// baseline (187.203 us; speedup 1.0000x reference)
//
#include <hip/hip_runtime.h>
#include <cstdint>
#include <cstddef>

// Problem constants
#define NB 2
#define TT 1024
#define MMEM 1024
#define SS 2048   // M + T
#define FF 1024
#define NHD 16    // heads
#define HD 64    // head dim

typedef __attribute__((ext_vector_type(8))) short bf16x8;
typedef __attribute__((ext_vector_type(4))) float f32x4;

__device__ __forceinline__ float bf2f(short s){
  unsigned u = ((unsigned)(unsigned short)s) << 16;
  float f; __builtin_memcpy(&f, &u, 4); return f;
}
__device__ __forceinline__ short f2bf(float f){
  unsigned u; __builtin_memcpy(&u, &f, 4);
  u += 0x7fffu + ((u >> 16) & 1u);   // RNE
  return (short)(u >> 16);
}

// async global->LDS, 16 B per lane; LDS dest must be WAVE-UNIFORM base,
// HW scatters lane i to base + i*16 (m104).
typedef const __attribute__((address_space(1))) void gv_t;
typedef __attribute__((address_space(3))) void lv_t;
__device__ __forceinline__ void stage16(const void* g, void* l){
  __builtin_amdgcn_global_load_lds((gv_t*)g, (lv_t*)l, 16, 0, 0);
}

// LDS byte offset of a generic pointer into __shared__ (HK lds_byte pattern).
typedef __attribute__((address_space(3))) const short ls3_t;
__device__ __forceinline__ unsigned lds_off(const short* p){
  return (unsigned)(size_t)(ls3_t*)p;
}

// inline-asm ds_read_b128. No "memory" clobber — the compiler must NOT see an
// LDS-read dependency on the outstanding global_load_lds queue, or it inserts
// its own s_waitcnt vmcnt(0) (the R11-R13 silent drain). Ordering is manual:
// counted vmcnt + s_barrier + sched_barrier(0), lgkmcnt(0)+sched_barrier(0)
// before the consuming MFMAs (rule #18).
template<int OFF>
__device__ __forceinline__ bf16x8 ds_read16(unsigned a){
  bf16x8 d;
  if constexpr (OFF == 0)
    asm volatile("ds_read_b128 %0, %1" : "=v"(d) : "v"(a));
  else
    asm volatile("ds_read_b128 %0, %1 offset:2048" : "=v"(d) : "v"(a));
  return d;
}

// ---------------- merged prep kernel ----------------
// build_inputs + transpose_cast5 + scan fused into ONE launch (R15).
#define NKVB 6144
#define NTRB 5120

__global__ __launch_bounds__(256) void prep_kernel(
    const float* __restrict__ mem, const float* __restrict__ x,
    const float* __restrict__ rel,
    const int* __restrict__ episode_idx, const int* __restrict__ dones,
    const float* __restrict__ w0, const float* __restrict__ w1,
    const float* __restrict__ w2, const float* __restrict__ w3,
    const float* __restrict__ w4,
    short* __restrict__ kv, short* __restrict__ relo,
    short* __restrict__ o0, short* __restrict__ o1,
    short* __restrict__ o2, short* __restrict__ o3, short* __restrict__ o4,
    int* __restrict__ ki, int2* __restrict__ ranges){
  const int blk = blockIdx.x;
  const int tid = threadIdx.x;

  if (blk < NKVB){
    // ---- pack: kv_bf = bf16(concat(memory, x)); rel_bf = bf16(rel) ----
    int i = blk * 256 + tid;  // float4 index
    const int nkv = NB * SS * FF / 4;
    const float* src; short* dst;
    if (i < nkv){
      int idx = i * 4;
      int row = idx >> 10, col = idx & 1023;
      int b = row >> 11, s = row & 2047;
      src = (s < MMEM) ? (mem + ((size_t)b*MMEM + s)*FF + col)
                       : (x   + ((size_t)b*TT + (s - MMEM))*FF + col);
      dst = kv + (size_t)i * 4;
    } else {
      int j = i - nkv;
      src = rel + (size_t)j * 4;
      dst = relo + (size_t)j * 4;
    }
    float4 v = *(const float4*)src;
    short4 o; o.x = f2bf(v.x); o.y = f2bf(v.y); o.z = f2bf(v.z); o.w = f2bf(v.w);
    *(short4*)dst = o;
    return;
  }

  if (blk < NKVB + NTRB){
    // ---- transpose-cast: out_z[c][r] = bf16(in_z[r][c]), 1024x1024 ----
    const int j = blk - NKVB;
    const int z5 = j >> 10;
    const int rem = j & 1023;
    const int by5 = rem >> 5, bx5 = rem & 31;
    const float* in; short* out;
    switch (z5){
      case 0: in = w0; out = o0; break;
      case 1: in = w1; out = o1; break;
      case 2: in = w2; out = o2; break;
      case 3: in = w3; out = o3; break;
      default: in = w4; out = o4; break;
    }
    __shared__ float tile[32][33];
    const int bx = bx5 * 32, by = by5 * 32;
    const int tx = tid & 31, ty = tid >> 5;
    for (int jj = ty; jj < 32; jj += 8)
      tile[jj][tx] = in[(size_t)(by + jj)*1024 + bx + tx];
    __syncthreads();
    for (int jj = ty; jj < 32; jj += 8)
      out[(size_t)(bx + jj)*1024 + by + tx] = f2bf(tile[tx][jj]);
    return;
  }

  // ---- scan (256 threads): ki + per-16-row-group valid-key ranges ----
  {
    const int b = blk - (NKVB + NTRB);
    __shared__ int kis[SS];
    __shared__ int wsum[4];
    const int t = tid;
    const int lane = t & 63, wv = t >> 6;
    #pragma unroll
    for (int j = 0; j < 4; j++) kis[t*4 + j] = episode_idx[b*MMEM + t*4 + j];
    int d[4]; int s = 0;
    #pragma unroll
    for (int j = 0; j < 4; j++){ d[j] = dones[b*TT + t*4 + j]; s += d[j]; }
    int v = s;
    #pragma unroll
    for (int off = 1; off < 64; off <<= 1){
      int tmp = __shfl_up(v, off, 64);
      if (lane >= off) v += tmp;
    }
    if (lane == 63) wsum[wv] = v;
    __syncthreads();                      // kis[0:1024] + wsum visible
    int add = 0;
    for (int w = 0; w < wv; w++) add += wsum[w];
    const int base = kis[MMEM - 1];
    int run = add + v - s;                // exclusive prefix before this thread
    #pragma unroll
    for (int j = 0; j < 4; j++){
      run += d[j];
      const int q = base + run;
      kis[MMEM + t*4 + j] = q;
      ki[b*SS + MMEM + t*4 + j] = q;
      ki[b*SS + t*4 + j] = kis[t*4 + j];
    }
    __syncthreads();
    if (t < 64){
      const int qlo = kis[MMEM + t*16];
      const int qhi = kis[MMEM + t*16 + 15];
      int lo = 0, hi = SS;
      while (lo < hi){ int mid = (lo + hi) >> 1; if (kis[mid] < qlo) lo = mid + 1; else hi = mid; }
      const int s_lo = lo;
      lo = 0; hi = SS;
      const int tgt = qhi + 1;
      while (lo < hi){ int mid = (lo + hi) >> 1; if (kis[mid] < tgt) lo = mid + 1; else hi = mid; }
      int s_hi = lo;                              // exclusive
      const int cap = t*16 + 15 + MMEM + 1;       // causal cap
      if (s_hi > cap) s_hi = cap;
      ranges[(b << 6) + t] = make_int2(s_lo, s_hi);
    }
  }
}

// uk[b,n,s] = sum_h u[n,h]*k[b,s,n,h];  vr[n,j] = sum_h v[n,h]*r[j,n,h]
__global__ void bias_tables(const short* __restrict__ kbf, const short* __restrict__ rbf,
                            const float* __restrict__ u, const float* __restrict__ v,
                            float* __restrict__ uk, float* __restrict__ vr){
  int i = blockIdx.x * blockDim.x + threadIdx.x;
  const short* p; const float* w; float* outp;
  if (i < NB * NHD * SS){
    int s = i & 2047, n = (i >> 11) & 15, b = i >> 15;
    p = kbf + (size_t)(b * SS + s) * 1024 + n * 64;
    w = u + n * 64;
    outp = uk + (size_t)(b * NHD + n) * SS + s;
  } else {
    int j = i - NB * NHD * SS;
    if (j >= NHD * SS) return;
    int jj = j & 2047, n = j >> 11;
    p = rbf + (size_t)jj * 1024 + n * 64;
    w = v + n * 64;
    outp = vr + (size_t)n * SS + jj;
  }
  float acc = 0.f;
  #pragma unroll
  for (int c = 0; c < 8; c++){
    bf16x8 kv8 = *(const bf16x8*)(p + c * 8);
    float4 w0 = *(const float4*)(w + c * 8);
    float4 w1 = *(const float4*)(w + c * 8 + 4);
    acc += bf2f(kv8[0])*w0.x + bf2f(kv8[1])*w0.y + bf2f(kv8[2])*w0.z + bf2f(kv8[3])*w0.w
         + bf2f(kv8[4])*w1.x + bf2f(kv8[5])*w1.y + bf2f(kv8[6])*w1.z + bf2f(kv8[7])*w1.w;
  }
  *outp = acc;
}

// ------------- 64x64 GEMM core, BK=64, triple-buffer depth-2, ASM ds_read ---
// R14/R15 core (verified best). Used by z=1 (q), z=2 (rbf) and out_gemm.
__device__ __forceinline__ void gemm_core_64x64(const short* __restrict__ A,
                                                const short* __restrict__ BT,
                                                int row0, int col0,
                                                short* As, short* Bs,
                                                f32x4 (&acc)[2][2]){
  const int tid = threadIdx.x;
  const int lane = tid & 63, wv = tid >> 6;
  const int lcol = lane & 15, quad = lane >> 4;
  const int wr = (wv >> 1) * 32, wc = (wv & 1) * 32;
  const int sw = lcol & 7;
  const int ch0 = (quad ^ sw) * 8;
  const int ch1 = ((4 + quad) ^ sw) * 8;

  #pragma unroll
  for (int r = 0; r < 2; r++)
    #pragma unroll
    for (int c = 0; c < 2; c++) acc[r][c] = (f32x4){0.f, 0.f, 0.f, 0.f};

  const int rs = tid >> 3, ps = tid & 7;
  const int ls = ps ^ (rs & 7);
  const short* gA = A  + (size_t)(row0 + rs) * 1024 + ls * 8;
  const short* gB = BT + (size_t)(col0 + rs) * 1024 + ls * 8;

  auto STAGE = [&](int k0, int bi){
    short* a = As + bi * 4096 + wv * 512;   // wave-uniform; HW adds lane*16B
    short* b = Bs + bi * 4096 + wv * 512;
    stage16(gA + k0,         a);
    stage16(gA + 32768 + k0, a + 2048);     // rows +32
    stage16(gB + k0,         b);
    stage16(gB + 32768 + k0, b + 2048);
  };

  const unsigned oa0 = lds_off(As) + (unsigned)(((wr + lcol) * 64 + ch0) * 2);
  const unsigned oa1 = lds_off(As) + (unsigned)(((wr + lcol) * 64 + ch1) * 2);
  const unsigned ob0 = lds_off(Bs) + (unsigned)(((wc + lcol) * 64 + ch0) * 2);
  const unsigned ob1 = lds_off(Bs) + (unsigned)(((wc + lcol) * 64 + ch1) * 2);

  // prologue: tiles 0,1 in flight (8 loads/thread outstanding)
  STAGE(0, 0);
  STAGE(64, 1);

  #pragma unroll 1
  for (int i = 0; i < 16; ++i){
    const int cur = i - (i / 3) * 3;        // i % 3
    if (i <= 13){
      const int nb = (i + 2) - ((i + 2) / 3) * 3;
      STAGE((i + 2) << 6, nb);
      asm volatile("s_waitcnt vmcnt(8)" ::: "memory");  // tile i landed; 8 in flight
    } else if (i == 14){
      asm volatile("s_waitcnt vmcnt(4)" ::: "memory");
    } else {
      asm volatile("s_waitcnt vmcnt(0)" ::: "memory");
    }
    __builtin_amdgcn_s_barrier();           // all waves' portions of tile i landed
    __builtin_amdgcn_sched_barrier(0);      // nothing crosses into the read region
    const unsigned bo = (unsigned)(cur * 8192);
    bf16x8 b00 = ds_read16<0>(ob0 + bo);
    bf16x8 b01 = ds_read16<0>(ob1 + bo);
    bf16x8 b10 = ds_read16<2048>(ob0 + bo);   // row +16
    bf16x8 b11 = ds_read16<2048>(ob1 + bo);
    bf16x8 a00 = ds_read16<0>(oa0 + bo);
    bf16x8 a01 = ds_read16<0>(oa1 + bo);
    bf16x8 a10 = ds_read16<2048>(oa0 + bo);   // row +16
    bf16x8 a11 = ds_read16<2048>(oa1 + bo);
    asm volatile("s_waitcnt lgkmcnt(0)" ::: "memory");  // ds_reads complete
    __builtin_amdgcn_sched_barrier(0);      // rule #18: pin MFMAs after the wait
    acc[0][0] = __builtin_amdgcn_mfma_f32_16x16x32_bf16(a00, b00, acc[0][0], 0, 0, 0);
    acc[0][0] = __builtin_amdgcn_mfma_f32_16x16x32_bf16(a01, b01, acc[0][0], 0, 0, 0);
    acc[0][1] = __builtin_amdgcn_mfma_f32_16x16x32_bf16(a00, b10, acc[0][1], 0, 0, 0);
    acc[0][1] = __builtin_amdgcn_mfma_f32_16x16x32_bf16(a01, b11, acc[0][1], 0, 0, 0);
    acc[1][0] = __builtin_amdgcn_mfma_f32_16x16x32_bf16(a10, b00, acc[1][0], 0, 0, 0);
    acc[1][0] = __builtin_amdgcn_mfma_f32_16x16x32_bf16(a11, b01, acc[1][0], 0, 0, 0);
    acc[1][1] = __builtin_amdgcn_mfma_f32_16x16x32_bf16(a10, b10, acc[1][1], 0, 0, 0);
    acc[1][1] = __builtin_amdgcn_mfma_f32_16x16x32_bf16(a11, b11, acc[1][1], 0, 0, 0);
    __builtin_amdgcn_sched_barrier(0);      // keep MFMAs inside this iteration
    __builtin_amdgcn_s_barrier();           // buf[cur] safe to overwrite
  }
}

// ----- 64x64 DUAL-B GEMM core (R19): stage A once, compute A@Bk and A@Bv ----
// 16 MFMA per barrier pair; halves kv A-traffic. 48 KB LDS -> 3 blocks/CU.
__device__ __forceinline__ void gemm_core_64x64_dual(const short* __restrict__ A,
                                                     const short* __restrict__ BkT,
                                                     const short* __restrict__ BvT,
                                                     int row0, int col0,
                                                     short* As, short* Bks, short* Bvs,
                                                     f32x4 (&accK)[2][2], f32x4 (&accV)[2][2]){
  const int tid = threadIdx.x;
  const int lane = tid & 63, wv = tid >> 6;
  const int lcol = lane & 15, quad = lane >> 4;
  const int wr = (wv >> 1) * 32, wc = (wv & 1) * 32;
  const int sw = lcol & 7;
  const int ch0 = (quad ^ sw) * 8;
  const int ch1 = ((4 + quad) ^ sw) * 8;

  #pragma unroll
  for (int r = 0; r < 2; r++)
    #pragma unroll
    for (int c = 0; c < 2; c++){
      accK[r][c] = (f32x4){0.f, 0.f, 0.f, 0.f};
      accV[r][c] = (f32x4){0.f, 0.f, 0.f, 0.f};
    }

  const int rs = tid >> 3, ps = tid & 7;
  const int ls = ps ^ (rs & 7);
  const short* gA  = A   + (size_t)(row0 + rs) * 1024 + ls * 8;
  const short* gBk = BkT + (size_t)(col0 + rs) * 1024 + ls * 8;
  const short* gBv = BvT + (size_t)(col0 + rs) * 1024 + ls * 8;

  auto STAGE = [&](int k0, int bi){
    short* a  = As  + bi * 4096 + wv * 512;  // wave-uniform; HW adds lane*16B
    short* bk = Bks + bi * 4096 + wv * 512;
    short* bv = Bvs + bi * 4096 + wv * 512;
    stage16(gA + k0,          a);
    stage16(gA + 32768 + k0,  a + 2048);     // rows +32
    stage16(gBk + k0,         bk);
    stage16(gBk + 32768 + k0, bk + 2048);
    stage16(gBv + k0,         bv);
    stage16(gBv + 32768 + k0, bv + 2048);
  };

  const unsigned oa0  = lds_off(As)  + (unsigned)(((wr + lcol) * 64 + ch0) * 2);
  const unsigned oa1  = lds_off(As)  + (unsigned)(((wr + lcol) * 64 + ch1) * 2);
  const unsigned obk0 = lds_off(Bks) + (unsigned)(((wc + lcol) * 64 + ch0) * 2);
  const unsigned obk1 = lds_off(Bks) + (unsigned)(((wc + lcol) * 64 + ch1) * 2);
  const unsigned obv0 = lds_off(Bvs) + (unsigned)(((wc + lcol) * 64 + ch0) * 2);
  const unsigned obv1 = lds_off(Bvs) + (unsigned)(((wc + lcol) * 64 + ch1) * 2);

  // prologue: tile 0 in flight (6 loads/thread outstanding)
  STAGE(0, 0);

  #pragma unroll 1
  for (int i = 0; i < 16; ++i){
    const int cur = i & 1;
    if (i < 15){
      STAGE((i + 1) << 6, cur ^ 1);
      asm volatile("s_waitcnt vmcnt(6)" ::: "memory");  // tile i landed; 6 in flight
    } else {
      asm volatile("s_waitcnt vmcnt(0)" ::: "memory");
    }
    __builtin_amdgcn_s_barrier();           // all waves' portions of tile i landed
    __builtin_amdgcn_sched_barrier(0);      // nothing crosses into the read region
    const unsigned bo = (unsigned)(cur * 8192);
    bf16x8 bk00 = ds_read16<0>(obk0 + bo);
    bf16x8 bk01 = ds_read16<0>(obk1 + bo);
    bf16x8 bk10 = ds_read16<2048>(obk0 + bo);  // row +16
    bf16x8 bk11 = ds_read16<2048>(obk1 + bo);
    bf16x8 bv00 = ds_read16<0>(obv0 + bo);
    bf16x8 bv01 = ds_read16<0>(obv1 + bo);
    bf16x8 bv10 = ds_read16<2048>(obv0 + bo);
    bf16x8 bv11 = ds_read16<2048>(obv1 + bo);
    bf16x8 a00  = ds_read16<0>(oa0 + bo);
    bf16x8 a01  = ds_read16<0>(oa1 + bo);
    bf16x8 a10  = ds_read16<2048>(oa0 + bo);
    bf16x8 a11  = ds_read16<2048>(oa1 + bo);
    asm volatile("s_waitcnt lgkmcnt(0)" ::: "memory");  // ds_reads complete
    __builtin_amdgcn_sched_barrier(0);      // rule #18: pin MFMAs after the wait
    accK[0][0] = __builtin_amdgcn_mfma_f32_16x16x32_bf16(a00, bk00, accK[0][0], 0, 0, 0);
    accK[0][0] = __builtin_amdgcn_mfma_f32_16x16x32_bf16(a01, bk01, accK[0][0], 0, 0, 0);
    accK[0][1] = __builtin_amdgcn_mfma_f32_16x16x32_bf16(a00, bk10, accK[0][1], 0, 0, 0);
    accK[0][1] = __builtin_amdgcn_mfma_f32_16x16x32_bf16(a01, bk11, accK[0][1], 0, 0, 0);
    accK[1][0] = __builtin_amdgcn_mfma_f32_16x16x32_bf16(a10, bk00, accK[1][0], 0, 0, 0);
    accK[1][0] = __builtin_amdgcn_mfma_f32_16x16x32_bf16(a11, bk01, accK[1][0], 0, 0, 0);
    accK[1][1] = __builtin_amdgcn_mfma_f32_16x16x32_bf16(a10, bk10, accK[1][1], 0, 0, 0);
    accK[1][1] = __builtin_amdgcn_mfma_f32_16x16x32_bf16(a11, bk11, accK[1][1], 0, 0, 0);
    accV[0][0] = __builtin_amdgcn_mfma_f32_16x16x32_bf16(a00, bv00, accV[0][0], 0, 0, 0);
    accV[0][0] = __builtin_amdgcn_mfma_f32_16x16x32_bf16(a01, bv01, accV[0][0], 0, 0, 0);
    accV[0][1] = __builtin_amdgcn_mfma_f32_16x16x32_bf16(a00, bv10, accV[0][1], 0, 0, 0);
    accV[0][1] = __builtin_amdgcn_mfma_f32_16x16x32_bf16(a01, bv11, accV[0][1], 0, 0, 0);
    accV[1][0] = __builtin_amdgcn_mfma_f32_16x16x32_bf16(a10, bv00, accV[1][0], 0, 0, 0);
    accV[1][0] = __builtin_amdgcn_mfma_f32_16x16x32_bf16(a11, bv01, accV[1][0], 0, 0, 0);
    accV[1][1] = __builtin_amdgcn_mfma_f32_16x16x32_bf16(a10, bv10, accV[1][1], 0, 0, 0);
    accV[1][1] = __builtin_amdgcn_mfma_f32_16x16x32_bf16(a11, bv11, accV[1][1], 0, 0, 0);
    __builtin_amdgcn_sched_barrier(0);      // keep MFMAs inside this iteration
    __builtin_amdgcn_s_barrier();           // buf[cur] safe to overwrite
  }
}

// Fused projection GEMM + XCD-locality swizzle (R15). R19 job map:
//   z=0: kbf + vT = kv @ {WkT, WvT}  (dual-B core; 4096 rows, bx<64)
//   z=1: qb  = x @ WqT   (bx<32)
//   z=2: rbf = rel @ WrT (bx<32) + row-band skip
__global__ __launch_bounds__(256) void proj_gemm(
    const short* __restrict__ kv, const short* __restrict__ relb,
    const short* __restrict__ WkT, const short* __restrict__ WvT,
    const short* __restrict__ WqT, const short* __restrict__ WrT,
    short* __restrict__ kbf, short* __restrict__ vT,
    short* __restrict__ qb, short* __restrict__ rbf,
    const int2* __restrict__ ranges){
  __shared__ __align__(16) short smem[3 * 8192];   // 48 KB, unioned layouts
  __shared__ int s_jm;
  const int z = blockIdx.z;
  const int iswz = blockIdx.x;               // [0,1024)
  const int xcd = iswz & 7, jj = iswz >> 3;
  const int bx = ((jj >> 4) << 3) | xcd;     // row tile [0,64)
  const int col0 = (jj & 15) * 64;           // col tile
  const int tid = threadIdx.x;
  const int lane = tid & 63, wv = tid >> 6;
  const int lcol = lane & 15, quad = lane >> 4;
  const int wr = (wv >> 1) * 32, wc = (wv & 1) * 32;

  if (z == 0){
    // ---- merged K+V projection (dual-B) ----
    const int row0 = bx * 64;
    const int bb = row0 >> 11;         // batch
    const int srow = row0 & 2047;      // s-index of tile start
    if (srow + 64 <= ranges[bb << 6].x) return;   // dead K/V rows
    f32x4 accK[2][2], accV[2][2];
    gemm_core_64x64_dual(kv, WkT, WvT, row0, col0,
                         smem, smem + 8192, smem + 16384, accK, accV);
    #pragma unroll
    for (int c = 0; c < 2; c++){
      const int cc = col0 + wc + c*16 + lcol;
      #pragma unroll
      for (int r = 0; r < 2; r++){
        #pragma unroll
        for (int ri = 0; ri < 4; ri++){
          const int rr = row0 + wr + r*16 + quad*4 + ri;
          kbf[(size_t)rr * 1024 + cc] = f2bf(accK[r][c][ri]);
          const int b = rr >> 11, s = rr & 2047;
          vT[(size_t)(((b << 4) + (cc >> 6)) * 64 + (cc & 63)) * 2048 + s] = f2bf(accV[r][c][ri]);
        }
      }
    }
    return;
  }

  const short* A; const short* BT;
  int row0, qbb = 0;
  if (z == 1){
    if (bx >= 32) return;
    qbb = bx >> 4;                       // batch
    A = kv + (size_t)(qbb * SS + MMEM) * 1024;   // x rows live inside kv
    row0 = (bx & 15) * 64;
    BT = WqT;
  } else {
    if (bx >= 32) return;
    row0 = bx * 64;
    // rbf row-band skip: attn reads R rows jr >= (s_lo(g) & ~63) - 16g + 1008
    if (tid == 0) s_jm = 0x7fffffff;
    __syncthreads();
    if (tid < 128){
      int2 e = ranges[tid];
      int jr = (e.x & ~63) - ((tid & 63) << 4) + 1008;
      atomicMin(&s_jm, jr);
    }
    __syncthreads();
    if (row0 + 64 <= s_jm) return;
    A = relb; BT = WrT;
  }

  f32x4 acc[2][2];
  gemm_core_64x64(A, BT, row0, col0, smem, smem + 12288, acc);

  #pragma unroll
  for (int c = 0; c < 2; c++){
    const int cc = col0 + wc + c*16 + lcol;
    #pragma unroll
    for (int r = 0; r < 2; r++){
      #pragma unroll
      for (int ri = 0; ri < 4; ri++){
        const int rr = row0 + wr + r*16 + quad*4 + ri;
        const float val = acc[r][c][ri];
        if (z == 1){
          qb[((size_t)(qbb * TT) + rr) * 1024 + cc] = f2bf(val);
        } else {
          rbf[(size_t)rr * 1024 + cc] = f2bf(val);
        }
      }
    }
  }
}

// Output projection: out = attn @ WoT + b_out (f32 out, 2048 rows)
__global__ __launch_bounds__(256) void out_gemm(const short* __restrict__ A,
                                                const short* __restrict__ BT,
                                                const float* __restrict__ bias,
                                                float* __restrict__ C){
  const int iswz = blockIdx.x;               // [0,512)
  const int xcd = iswz & 7, jj = iswz >> 3;
  const int p = ((jj >> 4) << 3) | xcd;      // row tile [0,32)
  const int row0 = p * 64, col0 = (jj & 15) * 64;
  __shared__ __align__(16) short As[3 * 64 * 64];
  __shared__ __align__(16) short Bs[3 * 64 * 64];
  f32x4 acc[2][2];
  gemm_core_64x64(A, BT, row0, col0, As, Bs, acc);

  const int lane = threadIdx.x & 63, wv = threadIdx.x >> 6;
  const int lcol = lane & 15, quad = lane >> 4;
  const int wr = (wv >> 1) * 32, wc = (wv & 1) * 32;
  #pragma unroll
  for (int c = 0; c < 2; c++){
    const int cc = col0 + wc + c*16 + lcol;
    const float bb = bias[cc];
    #pragma unroll
    for (int r = 0; r < 2; r++)
      #pragma unroll
      for (int ri = 0; ri < 4; ri++){
        const int rr = row0 + wr + r*16 + quad*4 + ri;
        C[(size_t)rr * 1024 + cc] = acc[r][c][ri] + bb;
      }
  }
}

// ---------------- flash attention: one wave per 16-row q-group --------------
// R20: cross-iteration software pipeline. attn is latency-bound (R5 counters:
// ~4 MB HBM only; all 2048 one-wave blocks co-resident -> wall ~ slowest-wave
// latency). R16 hid V-load latency under softmax; the K/R load exposure at
// the top of each iteration stayed serial. Now: consume kb/rbr in the MFMAs,
// snapshot the tile's scalars, then immediately issue tile i+1's K/R/scalar
// loads — their latency hides under softmax+LDS+PV. Plus T5 setprio(1)
// around both MFMA clusters (m191: helps independent 1-wave attn blocks).
// Per-tile arithmetic order unchanged -> bit-identical.
__global__ __launch_bounds__(64, 2) void attn_kernel(const short* __restrict__ qb,
                            const short* __restrict__ rbf,
                            const short* __restrict__ kk, const short* __restrict__ vT,
                            const int* __restrict__ ki,
                            const float* __restrict__ uk, const float* __restrict__ vr,
                            const int2* __restrict__ ranges,
                            short* __restrict__ attn_out){
  const int blk = blockIdx.x;
  const int xcd = blk & 7;
  const int idx = blk >> 3;                 // [0,256)
  const int bn  = (xcd << 2) | (idx >> 6);  // 4 (b,n) groups per XCD
  const int t16 = (idx & 63) * 16;
  const int n = bn & 15;
  const int b = bn >> 4;
  const int lane = threadIdx.x & 63;
  const int quad = lane >> 4, lcol = lane & 15;

  __shared__ __align__(16) short pb[16 * 72];

  const short* qp = qb + (size_t)(b * TT + t16 + lcol) * 1024 + n * 64 + quad * 8;
  bf16x8 aq0 = *(const bf16x8*)(qp);
  bf16x8 aq1 = *(const bf16x8*)(qp + 32);

  int trow[4], qi_r[4], sl[4];
  bool hi[4];
  #pragma unroll
  for (int r = 0; r < 4; r++){
    trow[r] = t16 + quad * 4 + r;
    qi_r[r] = ki[b * SS + MMEM + trow[r]];
    const int rt = quad * 4 + r;
    const int off = lcol + 15 - rt;
    sl[r] = quad * 16 + (off & 15);
    hi[r] = off >= 16;
  }

  float m_run[4], l_run[4];
  f32x4 o[4];
  #pragma unroll
  for (int r = 0; r < 4; r++){ m_run[r] = -1e30f; l_run[r] = 0.f; }
  #pragma unroll
  for (int c = 0; c < 4; c++) o[c] = (f32x4){0.f, 0.f, 0.f, 0.f};

  const float scale = 0.125f;
  const size_t vt_base = (size_t)((b * NHD + n) * HD);
  const short* rb_head = rbf + n * 64;
  const float* uk_row = uk + (size_t)(b * NHD + n) * SS;
  const float* vr_row = vr + (size_t)n * SS;

  const int2 rg = ranges[(b << 6) + (t16 >> 4)];
  const int kt0 = rg.x >> 6, kt1 = (rg.y - 1) >> 6;

  // pipeline registers: K/R/scalars for the NEXT tile to process
  bf16x8 kb[4][2], rbr[5][2];
  float ukc[4], vrj[5];
  int ki_c[4];

  // preload tile kt0
  {
    const int s0 = kt0 * 64;
    #pragma unroll
    for (int c = 0; c < 4; c++){
      const short* kp = kk + (size_t)(b * SS + s0 + 16 * c + lcol) * 1024 + n * 64 + quad * 8;
      kb[c][0] = *(const bf16x8*)(kp);
      kb[c][1] = *(const bf16x8*)(kp + 32);
      ukc[c] = uk_row[s0 + 16 * c + lcol];
      ki_c[c] = ki[b * SS + s0 + 16 * c + lcol];
    }
    const int j0 = s0 - t16 + 1008;   // >= 0 always
    #pragma unroll
    for (int c5 = 0; c5 < 5; c5++){
      int jr = j0 + 16 * c5 + lcol;
      jr = (jr > SS - 1) ? (SS - 1) : jr;   // clamped rows are causally masked
      const short* rp = rb_head + (size_t)jr * 1024 + quad * 8;
      rbr[c5][0] = *(const bf16x8*)(rp);
      rbr[c5][1] = *(const bf16x8*)(rp + 32);
      vrj[c5] = vr_row[jr];
    }
  }

  for (int kt = kt0; kt <= kt1; kt++){
    const int s0 = kt * 64;

    // ---- S = Q . K^T (consumes kb) ----
    __builtin_amdgcn_s_setprio(1);
    f32x4 sacc[4];
    #pragma unroll
    for (int c = 0; c < 4; c++){
      f32x4 z = (f32x4){0.f, 0.f, 0.f, 0.f};
      z = __builtin_amdgcn_mfma_f32_16x16x32_bf16(aq0, kb[c][0], z, 0, 0, 0);
      z = __builtin_amdgcn_mfma_f32_16x16x32_bf16(aq1, kb[c][1], z, 0, 0, 0);
      sacc[c] = z;
    }
    // ---- D = Q . R^T (+ vr column bias) (consumes rbr, vrj) ----
    f32x4 Dw[5];
    #pragma unroll
    for (int c5 = 0; c5 < 5; c5++){
      f32x4 z = (f32x4){0.f, 0.f, 0.f, 0.f};
      z = __builtin_amdgcn_mfma_f32_16x16x32_bf16(aq0, rbr[c5][0], z, 0, 0, 0);
      z = __builtin_amdgcn_mfma_f32_16x16x32_bf16(aq1, rbr[c5][1], z, 0, 0, 0);
      const float vv = vrj[c5];
      #pragma unroll
      for (int r = 0; r < 4; r++) z[r] += vv;
      Dw[c5] = z;
    }
    __builtin_amdgcn_s_setprio(0);

    // snapshot current tile's scalars (pipeline regs get overwritten below)
    float ukcur[4]; int kicur[4];
    #pragma unroll
    for (int c = 0; c < 4; c++){ ukcur[c] = ukc[c]; kicur[c] = ki_c[c]; }

    // ---- issue V loads for CURRENT tile (latency hides under softmax) ----
    bf16x8 vb[4][2];
    #pragma unroll
    for (int c = 0; c < 4; c++){
      const short* vtp = vT + (vt_base + c * 16 + lcol) * (size_t)SS + s0 + quad * 8;
      vb[c][0] = *(const bf16x8*)(vtp);
      vb[c][1] = *(const bf16x8*)(vtp + 32);
    }

    // ---- prefetch NEXT tile's K/R/scalars (hides under softmax+LDS+PV) ----
    if (kt < kt1){
      const int s1 = s0 + 64;
      #pragma unroll
      for (int c = 0; c < 4; c++){
        const short* kp = kk + (size_t)(b * SS + s1 + 16 * c + lcol) * 1024 + n * 64 + quad * 8;
        kb[c][0] = *(const bf16x8*)(kp);
        kb[c][1] = *(const bf16x8*)(kp + 32);
        ukc[c] = uk_row[s1 + 16 * c + lcol];
        ki_c[c] = ki[b * SS + s1 + 16 * c + lcol];
      }
      const int j1 = s1 - t16 + 1008;
      #pragma unroll
      for (int c5 = 0; c5 < 5; c5++){
        int jr = j1 + 16 * c5 + lcol;
        jr = (jr > SS - 1) ? (SS - 1) : jr;
        const short* rp = rb_head + (size_t)jr * 1024 + quad * 8;
        rbr[c5][0] = *(const bf16x8*)(rp);
        rbr[c5][1] = *(const bf16x8*)(rp + 32);
        vrj[c5] = vr_row[jr];
      }
    }

    // ---- bias shift (Toeplitz) + mask + logits ----
    float p[4][4];
    float rowmax[4];
    #pragma unroll
    for (int r = 0; r < 4; r++) rowmax[r] = -1e30f;
    #pragma unroll
    for (int c = 0; c < 4; c++){
      const int s = s0 + 16 * c + lcol;
      #pragma unroll
      for (int r = 0; r < 4; r++){
        const float v0 = __shfl(Dw[c][r], sl[r], 64);
        const float v1 = __shfl(Dw[c + 1][r], sl[r], 64);
        const float bd = hi[r] ? v1 : v0;
        float lg = (sacc[c][r] + ukcur[c] + bd) * scale;
        const bool valid = (s <= trow[r] + MMEM) && (kicur[c] == qi_r[r]);
        lg = valid ? lg : -1e30f;
        p[c][r] = lg;
        rowmax[r] = fmaxf(rowmax[r], lg);
      }
    }
    // ---- online softmax ----
    #pragma unroll
    for (int r = 0; r < 4; r++){
      float vmx = rowmax[r];
      #pragma unroll
      for (int off = 1; off < 16; off <<= 1) vmx = fmaxf(vmx, __shfl_xor(vmx, off, 64));
      float mnew = fmaxf(m_run[r], vmx);
      float alpha = __expf(m_run[r] - mnew);
      m_run[r] = mnew;
      l_run[r] *= alpha;
      #pragma unroll
      for (int c = 0; c < 4; c++) o[c][r] *= alpha;
    }
    float psum[4] = {0.f, 0.f, 0.f, 0.f};
    #pragma unroll
    for (int c = 0; c < 4; c++)
      #pragma unroll
      for (int r = 0; r < 4; r++){
        float pv = __expf(p[c][r] - m_run[r]);
        p[c][r] = pv;
        psum[r] += pv;
      }
    #pragma unroll
    for (int r = 0; r < 4; r++){
      float vs = psum[r];
      #pragma unroll
      for (int off = 1; off < 16; off <<= 1) vs += __shfl_xor(vs, off, 64);
      l_run[r] += vs;
    }
    // ---- P: C-layout -> A-layout via LDS (wave-synchronous) ----
    #pragma unroll
    for (int c = 0; c < 4; c++)
      #pragma unroll
      for (int r = 0; r < 4; r++)
        pb[(quad * 4 + r) * 72 + 16 * c + lcol] = f2bf(p[c][r]);
    bf16x8 pa0 = *(const bf16x8*)(&pb[lcol * 72 + quad * 8]);
    bf16x8 pa1 = *(const bf16x8*)(&pb[lcol * 72 + 32 + quad * 8]);
    // ---- O += P . V ----
    __builtin_amdgcn_s_setprio(1);
    #pragma unroll
    for (int c = 0; c < 4; c++){
      o[c] = __builtin_amdgcn_mfma_f32_16x16x32_bf16(pa0, vb[c][0], o[c], 0, 0, 0);
      o[c] = __builtin_amdgcn_mfma_f32_16x16x32_bf16(pa1, vb[c][1], o[c], 0, 0, 0);
    }
    __builtin_amdgcn_s_setprio(0);
  }

  // ---- epilogue: normalize, store bf16 attn [B*T, N*H] ----
  #pragma unroll
  for (int r = 0; r < 4; r++){
    const float inv = 1.f / l_run[r];
    const int t = trow[r];
    #pragma unroll
    for (int c = 0; c < 4; c++)
      attn_out[(size_t)(b * TT + t) * 1024 + n * 64 + c * 16 + lcol] = f2bf(o[c][r] * inv);
  }
}

// ---------------- launcher ----------------
extern "C" void kernel_launch(void* const* d_in, const int* in_sizes, int n_in,
                              void* d_out, int out_size, void* d_ws, size_t ws_size,
                              hipStream_t stream){
  const float* x      = (const float*)d_in[0];
  const float* rel    = (const float*)d_in[1];
  const float* memory = (const float*)d_in[2];
  const int*   episode_idx = (const int*)d_in[3];
  const int*   dones  = (const int*)d_in[4];
  const float* Wq  = (const float*)d_in[5];
  const float* Wk  = (const float*)d_in[6];
  const float* Wv  = (const float*)d_in[7];
  const float* Wr  = (const float*)d_in[8];
  const float* u   = (const float*)d_in[9];
  const float* v   = (const float*)d_in[10];
  const float* Wout  = (const float*)d_in[11];
  const float* b_out = (const float*)d_in[12];
  float* out = (float*)d_out;

  char* ws = (char*)d_ws;
  size_t off = 0;
  auto alloc = [&](size_t bytes) -> char* {
    char* p = ws + off;
    off += (bytes + 255) & ~(size_t)255;
    return p;
  };
  short* kv_bf  = (short*)alloc((size_t)NB * SS * FF * 2);
  short* rel_bf = (short*)alloc((size_t)SS * FF * 2);
  short* WqT    = (short*)alloc((size_t)FF * 1024 * 2);
  short* WkT    = (short*)alloc((size_t)FF * 1024 * 2);
  short* WvT    = (short*)alloc((size_t)FF * 1024 * 2);
  short* WrT    = (short*)alloc((size_t)FF * 1024 * 2);
  short* WoT    = (short*)alloc((size_t)FF * 1024 * 2);
  short* qbuf   = (short*)alloc((size_t)NB * TT * 1024 * 2);
  short* kbf    = (short*)alloc((size_t)NB * SS * 1024 * 2);
  short* vTb    = (short*)alloc((size_t)NB * SS * 1024 * 2);
  short* rbf    = (short*)alloc((size_t)SS * 1024 * 2);
  int*   ki     = (int*)  alloc((size_t)NB * SS * 4);
  int2*  ranges = (int2*) alloc((size_t)NB * 64 * 8);
  float* ukT    = (float*)alloc((size_t)NB * NHD * SS * 4);
  float* vrT    = (float*)alloc((size_t)NHD * SS * 4);
  short* attn   = (short*)alloc((size_t)NB * TT * 1024 * 2);
  (void)ws_size; (void)in_sizes; (void)n_in; (void)out_size;

  // merged prep: pack + 5x transpose-cast + scan (one launch, R15)
  prep_kernel<<<NKVB + NTRB + NB, 256, 0, stream>>>(
      memory, x, rel, episode_idx, dones,
      Wq, Wk, Wv, Wr, Wout,
      kv_bf, rel_bf, WqT, WkT, WvT, WrT, WoT, ki, ranges);

  // fused projections: z=0 dual-B K+V merge (R19), z=1 q, z=2 rbf
  proj_gemm<<<dim3(1024, 1, 3), 256, 0, stream>>>(kv_bf, rel_bf,
                                                  WkT, WvT, WqT, WrT,
                                                  kbf, vTb, qbuf, rbf, ranges);

  // u·k / v·r column-bias tables
  bias_tables<<<(NB*NHD*SS + NHD*SS + 255)/256, 256, 0, stream>>>(kbf, rbf, u, v, ukT, vrT);

  // attention: cross-iteration K/R pipeline + setprio (R20)
  attn_kernel<<<2048, 64, 0, stream>>>(qbuf, rbf, kbf, vTb, ki, ukT, vrT, ranges, attn);

  // output projection (XCD-locality swizzle, triple-buffer core)
  out_gemm<<<512, 256, 0, stream>>>(attn, WoT, b_out, out);
}

// Round 12
// 183.171 us; speedup vs baseline: 1.0220x; 1.0220x over previous
//
#include <hip/hip_runtime.h>
#include <cstdint>
#include <cstddef>

// Problem constants
#define NB 2
#define TT 1024
#define MMEM 1024
#define SS 2048   // M + T
#define FF 1024
#define NHD 16    // heads
#define HD 64    // head dim

typedef __attribute__((ext_vector_type(8))) short bf16x8;
typedef __attribute__((ext_vector_type(4))) float f32x4;

__device__ __forceinline__ float bf2f(short s){
  unsigned u = ((unsigned)(unsigned short)s) << 16;
  float f; __builtin_memcpy(&f, &u, 4); return f;
}
__device__ __forceinline__ short f2bf(float f){
  unsigned u; __builtin_memcpy(&u, &f, 4);
  u += 0x7fffu + ((u >> 16) & 1u);   // RNE
  return (short)(u >> 16);
}

// async global->LDS, 16 B per lane; LDS dest must be WAVE-UNIFORM base,
// HW scatters lane i to base + i*16 (m104).
typedef const __attribute__((address_space(1))) void gv_t;
typedef __attribute__((address_space(3))) void lv_t;
__device__ __forceinline__ void stage16(const void* g, void* l){
  __builtin_amdgcn_global_load_lds((gv_t*)g, (lv_t*)l, 16, 0, 0);
}

// LDS byte offset of a generic pointer into __shared__ (HK lds_byte pattern).
typedef __attribute__((address_space(3))) const short ls3_t;
__device__ __forceinline__ unsigned lds_off(const short* p){
  return (unsigned)(size_t)(ls3_t*)p;
}

// inline-asm ds_read_b128. No "memory" clobber — the compiler must NOT see an
// LDS-read dependency on the outstanding global_load_lds queue, or it inserts
// its own s_waitcnt vmcnt(0) (the R11-R13 silent drain). Ordering is manual:
// counted vmcnt + s_barrier + sched_barrier(0), lgkmcnt(0)+sched_barrier(0)
// before the consuming MFMAs (rule #18).
template<int OFF>
__device__ __forceinline__ bf16x8 ds_read16(unsigned a){
  bf16x8 d;
  if constexpr (OFF == 0)
    asm volatile("ds_read_b128 %0, %1" : "=v"(d) : "v"(a));
  else
    asm volatile("ds_read_b128 %0, %1 offset:2048" : "=v"(d) : "v"(a));
  return d;
}

// ---------------- merged prep kernel ----------------
// build_inputs + transpose_cast5 + scan fused into ONE launch (R15).
#define NKVB 6144
#define NTRB 5120

__global__ __launch_bounds__(256) void prep_kernel(
    const float* __restrict__ mem, const float* __restrict__ x,
    const float* __restrict__ rel,
    const int* __restrict__ episode_idx, const int* __restrict__ dones,
    const float* __restrict__ w0, const float* __restrict__ w1,
    const float* __restrict__ w2, const float* __restrict__ w3,
    const float* __restrict__ w4,
    short* __restrict__ kv, short* __restrict__ relo,
    short* __restrict__ o0, short* __restrict__ o1,
    short* __restrict__ o2, short* __restrict__ o3, short* __restrict__ o4,
    int* __restrict__ ki, int2* __restrict__ ranges){
  const int blk = blockIdx.x;
  const int tid = threadIdx.x;

  if (blk < NKVB){
    // ---- pack: kv_bf = bf16(concat(memory, x)); rel_bf = bf16(rel) ----
    int i = blk * 256 + tid;  // float4 index
    const int nkv = NB * SS * FF / 4;
    const float* src; short* dst;
    if (i < nkv){
      int idx = i * 4;
      int row = idx >> 10, col = idx & 1023;
      int b = row >> 11, s = row & 2047;
      src = (s < MMEM) ? (mem + ((size_t)b*MMEM + s)*FF + col)
                       : (x   + ((size_t)b*TT + (s - MMEM))*FF + col);
      dst = kv + (size_t)i * 4;
    } else {
      int j = i - nkv;
      src = rel + (size_t)j * 4;
      dst = relo + (size_t)j * 4;
    }
    float4 v = *(const float4*)src;
    short4 o; o.x = f2bf(v.x); o.y = f2bf(v.y); o.z = f2bf(v.z); o.w = f2bf(v.w);
    *(short4*)dst = o;
    return;
  }

  if (blk < NKVB + NTRB){
    // ---- transpose-cast: out_z[c][r] = bf16(in_z[r][c]), 1024x1024 ----
    const int j = blk - NKVB;
    const int z5 = j >> 10;
    const int rem = j & 1023;
    const int by5 = rem >> 5, bx5 = rem & 31;
    const float* in; short* out;
    switch (z5){
      case 0: in = w0; out = o0; break;
      case 1: in = w1; out = o1; break;
      case 2: in = w2; out = o2; break;
      case 3: in = w3; out = o3; break;
      default: in = w4; out = o4; break;
    }
    __shared__ float tile[32][33];
    const int bx = bx5 * 32, by = by5 * 32;
    const int tx = tid & 31, ty = tid >> 5;
    for (int jj = ty; jj < 32; jj += 8)
      tile[jj][tx] = in[(size_t)(by + jj)*1024 + bx + tx];
    __syncthreads();
    for (int jj = ty; jj < 32; jj += 8)
      out[(size_t)(bx + jj)*1024 + by + tx] = f2bf(tile[tx][jj]);
    return;
  }

  // ---- scan (256 threads): ki + per-16-row-group valid-key ranges ----
  {
    const int b = blk - (NKVB + NTRB);
    __shared__ int kis[SS];
    __shared__ int wsum[4];
    const int t = tid;
    const int lane = t & 63, wv = t >> 6;
    #pragma unroll
    for (int j = 0; j < 4; j++) kis[t*4 + j] = episode_idx[b*MMEM + t*4 + j];
    int d[4]; int s = 0;
    #pragma unroll
    for (int j = 0; j < 4; j++){ d[j] = dones[b*TT + t*4 + j]; s += d[j]; }
    int v = s;
    #pragma unroll
    for (int off = 1; off < 64; off <<= 1){
      int tmp = __shfl_up(v, off, 64);
      if (lane >= off) v += tmp;
    }
    if (lane == 63) wsum[wv] = v;
    __syncthreads();                      // kis[0:1024] + wsum visible
    int add = 0;
    for (int w = 0; w < wv; w++) add += wsum[w];
    const int base = kis[MMEM - 1];
    int run = add + v - s;                // exclusive prefix before this thread
    #pragma unroll
    for (int j = 0; j < 4; j++){
      run += d[j];
      const int q = base + run;
      kis[MMEM + t*4 + j] = q;
      ki[b*SS + MMEM + t*4 + j] = q;
      ki[b*SS + t*4 + j] = kis[t*4 + j];
    }
    __syncthreads();
    if (t < 64){
      const int qlo = kis[MMEM + t*16];
      const int qhi = kis[MMEM + t*16 + 15];
      int lo = 0, hi = SS;
      while (lo < hi){ int mid = (lo + hi) >> 1; if (kis[mid] < qlo) lo = mid + 1; else hi = mid; }
      const int s_lo = lo;
      lo = 0; hi = SS;
      const int tgt = qhi + 1;
      while (lo < hi){ int mid = (lo + hi) >> 1; if (kis[mid] < tgt) lo = mid + 1; else hi = mid; }
      int s_hi = lo;                              // exclusive
      const int cap = t*16 + 15 + MMEM + 1;       // causal cap
      if (s_hi > cap) s_hi = cap;
      ranges[(b << 6) + t] = make_int2(s_lo, s_hi);
    }
  }
}

// uk[b,n,s] = sum_h u[n,h]*k[b,s,n,h];  vr[n,j] = sum_h v[n,h]*r[j,n,h]
__global__ void bias_tables(const short* __restrict__ kbf, const short* __restrict__ rbf,
                            const float* __restrict__ u, const float* __restrict__ v,
                            float* __restrict__ uk, float* __restrict__ vr){
  int i = blockIdx.x * blockDim.x + threadIdx.x;
  const short* p; const float* w; float* outp;
  if (i < NB * NHD * SS){
    int s = i & 2047, n = (i >> 11) & 15, b = i >> 15;
    p = kbf + (size_t)(b * SS + s) * 1024 + n * 64;
    w = u + n * 64;
    outp = uk + (size_t)(b * NHD + n) * SS + s;
  } else {
    int j = i - NB * NHD * SS;
    if (j >= NHD * SS) return;
    int jj = j & 2047, n = j >> 11;
    p = rbf + (size_t)jj * 1024 + n * 64;
    w = v + n * 64;
    outp = vr + (size_t)n * SS + jj;
  }
  float acc = 0.f;
  #pragma unroll
  for (int c = 0; c < 8; c++){
    bf16x8 kv8 = *(const bf16x8*)(p + c * 8);
    float4 w0 = *(const float4*)(w + c * 8);
    float4 w1 = *(const float4*)(w + c * 8 + 4);
    acc += bf2f(kv8[0])*w0.x + bf2f(kv8[1])*w0.y + bf2f(kv8[2])*w0.z + bf2f(kv8[3])*w0.w
         + bf2f(kv8[4])*w1.x + bf2f(kv8[5])*w1.y + bf2f(kv8[6])*w1.z + bf2f(kv8[7])*w1.w;
  }
  *outp = acc;
}

// ------------- 64x64 GEMM core, BK=64, triple-buffer depth-2, ASM ds_read ---
// R14/R15 core (verified best). Used by z=1 (q), z=2 (rbf) and out_gemm.
__device__ __forceinline__ void gemm_core_64x64(const short* __restrict__ A,
                                                const short* __restrict__ BT,
                                                int row0, int col0,
                                                short* As, short* Bs,
                                                f32x4 (&acc)[2][2]){
  const int tid = threadIdx.x;
  const int lane = tid & 63, wv = tid >> 6;
  const int lcol = lane & 15, quad = lane >> 4;
  const int wr = (wv >> 1) * 32, wc = (wv & 1) * 32;
  const int sw = lcol & 7;
  const int ch0 = (quad ^ sw) * 8;
  const int ch1 = ((4 + quad) ^ sw) * 8;

  #pragma unroll
  for (int r = 0; r < 2; r++)
    #pragma unroll
    for (int c = 0; c < 2; c++) acc[r][c] = (f32x4){0.f, 0.f, 0.f, 0.f};

  const int rs = tid >> 3, ps = tid & 7;
  const int ls = ps ^ (rs & 7);
  const short* gA = A  + (size_t)(row0 + rs) * 1024 + ls * 8;
  const short* gB = BT + (size_t)(col0 + rs) * 1024 + ls * 8;

  auto STAGE = [&](int k0, int bi){
    short* a = As + bi * 4096 + wv * 512;   // wave-uniform; HW adds lane*16B
    short* b = Bs + bi * 4096 + wv * 512;
    stage16(gA + k0,         a);
    stage16(gA + 32768 + k0, a + 2048);     // rows +32
    stage16(gB + k0,         b);
    stage16(gB + 32768 + k0, b + 2048);
  };

  const unsigned oa0 = lds_off(As) + (unsigned)(((wr + lcol) * 64 + ch0) * 2);
  const unsigned oa1 = lds_off(As) + (unsigned)(((wr + lcol) * 64 + ch1) * 2);
  const unsigned ob0 = lds_off(Bs) + (unsigned)(((wc + lcol) * 64 + ch0) * 2);
  const unsigned ob1 = lds_off(Bs) + (unsigned)(((wc + lcol) * 64 + ch1) * 2);

  // prologue: tiles 0,1 in flight (8 loads/thread outstanding)
  STAGE(0, 0);
  STAGE(64, 1);

  #pragma unroll 1
  for (int i = 0; i < 16; ++i){
    const int cur = i - (i / 3) * 3;        // i % 3
    if (i <= 13){
      const int nb = (i + 2) - ((i + 2) / 3) * 3;
      STAGE((i + 2) << 6, nb);
      asm volatile("s_waitcnt vmcnt(8)" ::: "memory");  // tile i landed; 8 in flight
    } else if (i == 14){
      asm volatile("s_waitcnt vmcnt(4)" ::: "memory");
    } else {
      asm volatile("s_waitcnt vmcnt(0)" ::: "memory");
    }
    __builtin_amdgcn_s_barrier();           // all waves' portions of tile i landed
    __builtin_amdgcn_sched_barrier(0);      // nothing crosses into the read region
    const unsigned bo = (unsigned)(cur * 8192);
    bf16x8 b00 = ds_read16<0>(ob0 + bo);
    bf16x8 b01 = ds_read16<0>(ob1 + bo);
    bf16x8 b10 = ds_read16<2048>(ob0 + bo);   // row +16
    bf16x8 b11 = ds_read16<2048>(ob1 + bo);
    bf16x8 a00 = ds_read16<0>(oa0 + bo);
    bf16x8 a01 = ds_read16<0>(oa1 + bo);
    bf16x8 a10 = ds_read16<2048>(oa0 + bo);   // row +16
    bf16x8 a11 = ds_read16<2048>(oa1 + bo);
    asm volatile("s_waitcnt lgkmcnt(0)" ::: "memory");  // ds_reads complete
    __builtin_amdgcn_sched_barrier(0);      // rule #18: pin MFMAs after the wait
    acc[0][0] = __builtin_amdgcn_mfma_f32_16x16x32_bf16(a00, b00, acc[0][0], 0, 0, 0);
    acc[0][0] = __builtin_amdgcn_mfma_f32_16x16x32_bf16(a01, b01, acc[0][0], 0, 0, 0);
    acc[0][1] = __builtin_amdgcn_mfma_f32_16x16x32_bf16(a00, b10, acc[0][1], 0, 0, 0);
    acc[0][1] = __builtin_amdgcn_mfma_f32_16x16x32_bf16(a01, b11, acc[0][1], 0, 0, 0);
    acc[1][0] = __builtin_amdgcn_mfma_f32_16x16x32_bf16(a10, b00, acc[1][0], 0, 0, 0);
    acc[1][0] = __builtin_amdgcn_mfma_f32_16x16x32_bf16(a11, b01, acc[1][0], 0, 0, 0);
    acc[1][1] = __builtin_amdgcn_mfma_f32_16x16x32_bf16(a10, b10, acc[1][1], 0, 0, 0);
    acc[1][1] = __builtin_amdgcn_mfma_f32_16x16x32_bf16(a11, b11, acc[1][1], 0, 0, 0);
    __builtin_amdgcn_sched_barrier(0);      // keep MFMAs inside this iteration
    __builtin_amdgcn_s_barrier();           // buf[cur] safe to overwrite
  }
}

// ----- 64x64 DUAL-B GEMM core (R19): stage A once, compute A@Bk and A@Bv ----
// 16 MFMA per barrier pair; halves kv A-traffic. 48 KB LDS -> 3 blocks/CU.
__device__ __forceinline__ void gemm_core_64x64_dual(const short* __restrict__ A,
                                                     const short* __restrict__ BkT,
                                                     const short* __restrict__ BvT,
                                                     int row0, int col0,
                                                     short* As, short* Bks, short* Bvs,
                                                     f32x4 (&accK)[2][2], f32x4 (&accV)[2][2]){
  const int tid = threadIdx.x;
  const int lane = tid & 63, wv = tid >> 6;
  const int lcol = lane & 15, quad = lane >> 4;
  const int wr = (wv >> 1) * 32, wc = (wv & 1) * 32;
  const int sw = lcol & 7;
  const int ch0 = (quad ^ sw) * 8;
  const int ch1 = ((4 + quad) ^ sw) * 8;

  #pragma unroll
  for (int r = 0; r < 2; r++)
    #pragma unroll
    for (int c = 0; c < 2; c++){
      accK[r][c] = (f32x4){0.f, 0.f, 0.f, 0.f};
      accV[r][c] = (f32x4){0.f, 0.f, 0.f, 0.f};
    }

  const int rs = tid >> 3, ps = tid & 7;
  const int ls = ps ^ (rs & 7);
  const short* gA  = A   + (size_t)(row0 + rs) * 1024 + ls * 8;
  const short* gBk = BkT + (size_t)(col0 + rs) * 1024 + ls * 8;
  const short* gBv = BvT + (size_t)(col0 + rs) * 1024 + ls * 8;

  auto STAGE = [&](int k0, int bi){
    short* a  = As  + bi * 4096 + wv * 512;  // wave-uniform; HW adds lane*16B
    short* bk = Bks + bi * 4096 + wv * 512;
    short* bv = Bvs + bi * 4096 + wv * 512;
    stage16(gA + k0,          a);
    stage16(gA + 32768 + k0,  a + 2048);     // rows +32
    stage16(gBk + k0,         bk);
    stage16(gBk + 32768 + k0, bk + 2048);
    stage16(gBv + k0,         bv);
    stage16(gBv + 32768 + k0, bv + 2048);
  };

  const unsigned oa0  = lds_off(As)  + (unsigned)(((wr + lcol) * 64 + ch0) * 2);
  const unsigned oa1  = lds_off(As)  + (unsigned)(((wr + lcol) * 64 + ch1) * 2);
  const unsigned obk0 = lds_off(Bks) + (unsigned)(((wc + lcol) * 64 + ch0) * 2);
  const unsigned obk1 = lds_off(Bks) + (unsigned)(((wc + lcol) * 64 + ch1) * 2);
  const unsigned obv0 = lds_off(Bvs) + (unsigned)(((wc + lcol) * 64 + ch0) * 2);
  const unsigned obv1 = lds_off(Bvs) + (unsigned)(((wc + lcol) * 64 + ch1) * 2);

  // prologue: tile 0 in flight (6 loads/thread outstanding)
  STAGE(0, 0);

  #pragma unroll 1
  for (int i = 0; i < 16; ++i){
    const int cur = i & 1;
    if (i < 15){
      STAGE((i + 1) << 6, cur ^ 1);
      asm volatile("s_waitcnt vmcnt(6)" ::: "memory");  // tile i landed; 6 in flight
    } else {
      asm volatile("s_waitcnt vmcnt(0)" ::: "memory");
    }
    __builtin_amdgcn_s_barrier();           // all waves' portions of tile i landed
    __builtin_amdgcn_sched_barrier(0);      // nothing crosses into the read region
    const unsigned bo = (unsigned)(cur * 8192);
    bf16x8 bk00 = ds_read16<0>(obk0 + bo);
    bf16x8 bk01 = ds_read16<0>(obk1 + bo);
    bf16x8 bk10 = ds_read16<2048>(obk0 + bo);  // row +16
    bf16x8 bk11 = ds_read16<2048>(obk1 + bo);
    bf16x8 bv00 = ds_read16<0>(obv0 + bo);
    bf16x8 bv01 = ds_read16<0>(obv1 + bo);
    bf16x8 bv10 = ds_read16<2048>(obv0 + bo);
    bf16x8 bv11 = ds_read16<2048>(obv1 + bo);
    bf16x8 a00  = ds_read16<0>(oa0 + bo);
    bf16x8 a01  = ds_read16<0>(oa1 + bo);
    bf16x8 a10  = ds_read16<2048>(oa0 + bo);
    bf16x8 a11  = ds_read16<2048>(oa1 + bo);
    asm volatile("s_waitcnt lgkmcnt(0)" ::: "memory");  // ds_reads complete
    __builtin_amdgcn_sched_barrier(0);      // rule #18: pin MFMAs after the wait
    accK[0][0] = __builtin_amdgcn_mfma_f32_16x16x32_bf16(a00, bk00, accK[0][0], 0, 0, 0);
    accK[0][0] = __builtin_amdgcn_mfma_f32_16x16x32_bf16(a01, bk01, accK[0][0], 0, 0, 0);
    accK[0][1] = __builtin_amdgcn_mfma_f32_16x16x32_bf16(a00, bk10, accK[0][1], 0, 0, 0);
    accK[0][1] = __builtin_amdgcn_mfma_f32_16x16x32_bf16(a01, bk11, accK[0][1], 0, 0, 0);
    accK[1][0] = __builtin_amdgcn_mfma_f32_16x16x32_bf16(a10, bk00, accK[1][0], 0, 0, 0);
    accK[1][0] = __builtin_amdgcn_mfma_f32_16x16x32_bf16(a11, bk01, accK[1][0], 0, 0, 0);
    accK[1][1] = __builtin_amdgcn_mfma_f32_16x16x32_bf16(a10, bk10, accK[1][1], 0, 0, 0);
    accK[1][1] = __builtin_amdgcn_mfma_f32_16x16x32_bf16(a11, bk11, accK[1][1], 0, 0, 0);
    accV[0][0] = __builtin_amdgcn_mfma_f32_16x16x32_bf16(a00, bv00, accV[0][0], 0, 0, 0);
    accV[0][0] = __builtin_amdgcn_mfma_f32_16x16x32_bf16(a01, bv01, accV[0][0], 0, 0, 0);
    accV[0][1] = __builtin_amdgcn_mfma_f32_16x16x32_bf16(a00, bv10, accV[0][1], 0, 0, 0);
    accV[0][1] = __builtin_amdgcn_mfma_f32_16x16x32_bf16(a01, bv11, accV[0][1], 0, 0, 0);
    accV[1][0] = __builtin_amdgcn_mfma_f32_16x16x32_bf16(a10, bv00, accV[1][0], 0, 0, 0);
    accV[1][0] = __builtin_amdgcn_mfma_f32_16x16x32_bf16(a11, bv01, accV[1][0], 0, 0, 0);
    accV[1][1] = __builtin_amdgcn_mfma_f32_16x16x32_bf16(a10, bv10, accV[1][1], 0, 0, 0);
    accV[1][1] = __builtin_amdgcn_mfma_f32_16x16x32_bf16(a11, bv11, accV[1][1], 0, 0, 0);
    __builtin_amdgcn_sched_barrier(0);      // keep MFMAs inside this iteration
    __builtin_amdgcn_s_barrier();           // buf[cur] safe to overwrite
  }
}

// Fused projection GEMM + XCD-locality swizzle (R15). R19 job map:
//   z=0: kbf + vT = kv @ {WkT, WvT}  (dual-B core; 4096 rows, bx<64)
//   z=1: qb  = x @ WqT   (bx<32)
//   z=2: rbf = rel @ WrT (bx<32) + row-band skip
__global__ __launch_bounds__(256) void proj_gemm(
    const short* __restrict__ kv, const short* __restrict__ relb,
    const short* __restrict__ WkT, const short* __restrict__ WvT,
    const short* __restrict__ WqT, const short* __restrict__ WrT,
    short* __restrict__ kbf, short* __restrict__ vT,
    short* __restrict__ qb, short* __restrict__ rbf,
    const int2* __restrict__ ranges){
  __shared__ __align__(16) short smem[3 * 8192];   // 48 KB, unioned layouts
  __shared__ int s_jm;
  const int z = blockIdx.z;
  const int iswz = blockIdx.x;               // [0,1024)
  const int xcd = iswz & 7, jj = iswz >> 3;
  const int bx = ((jj >> 4) << 3) | xcd;     // row tile [0,64)
  const int col0 = (jj & 15) * 64;           // col tile
  const int tid = threadIdx.x;
  const int lane = tid & 63, wv = tid >> 6;
  const int lcol = lane & 15, quad = lane >> 4;
  const int wr = (wv >> 1) * 32, wc = (wv & 1) * 32;

  if (z == 0){
    // ---- merged K+V projection (dual-B) ----
    const int row0 = bx * 64;
    const int bb = row0 >> 11;         // batch
    const int srow = row0 & 2047;      // s-index of tile start
    if (srow + 64 <= ranges[bb << 6].x) return;   // dead K/V rows
    f32x4 accK[2][2], accV[2][2];
    gemm_core_64x64_dual(kv, WkT, WvT, row0, col0,
                         smem, smem + 8192, smem + 16384, accK, accV);
    #pragma unroll
    for (int c = 0; c < 2; c++){
      const int cc = col0 + wc + c*16 + lcol;
      #pragma unroll
      for (int r = 0; r < 2; r++){
        #pragma unroll
        for (int ri = 0; ri < 4; ri++){
          const int rr = row0 + wr + r*16 + quad*4 + ri;
          kbf[(size_t)rr * 1024 + cc] = f2bf(accK[r][c][ri]);
          const int b = rr >> 11, s = rr & 2047;
          vT[(size_t)(((b << 4) + (cc >> 6)) * 64 + (cc & 63)) * 2048 + s] = f2bf(accV[r][c][ri]);
        }
      }
    }
    return;
  }

  const short* A; const short* BT;
  int row0, qbb = 0;
  if (z == 1){
    if (bx >= 32) return;
    qbb = bx >> 4;                       // batch
    A = kv + (size_t)(qbb * SS + MMEM) * 1024;   // x rows live inside kv
    row0 = (bx & 15) * 64;
    BT = WqT;
  } else {
    if (bx >= 32) return;
    row0 = bx * 64;
    // rbf row-band skip: attn reads R rows jr >= (s_lo(g) & ~63) - 16g + 1008
    if (tid == 0) s_jm = 0x7fffffff;
    __syncthreads();
    if (tid < 128){
      int2 e = ranges[tid];
      int jr = (e.x & ~63) - ((tid & 63) << 4) + 1008;
      atomicMin(&s_jm, jr);
    }
    __syncthreads();
    if (row0 + 64 <= s_jm) return;
    A = relb; BT = WrT;
  }

  f32x4 acc[2][2];
  gemm_core_64x64(A, BT, row0, col0, smem, smem + 12288, acc);

  #pragma unroll
  for (int c = 0; c < 2; c++){
    const int cc = col0 + wc + c*16 + lcol;
    #pragma unroll
    for (int r = 0; r < 2; r++){
      #pragma unroll
      for (int ri = 0; ri < 4; ri++){
        const int rr = row0 + wr + r*16 + quad*4 + ri;
        const float val = acc[r][c][ri];
        if (z == 1){
          qb[((size_t)(qbb * TT) + rr) * 1024 + cc] = f2bf(val);
        } else {
          rbf[(size_t)rr * 1024 + cc] = f2bf(val);
        }
      }
    }
  }
}

// Output projection: out = attn @ WoT + b_out (f32 out, 2048 rows)
__global__ __launch_bounds__(256) void out_gemm(const short* __restrict__ A,
                                                const short* __restrict__ BT,
                                                const float* __restrict__ bias,
                                                float* __restrict__ C){
  const int iswz = blockIdx.x;               // [0,512)
  const int xcd = iswz & 7, jj = iswz >> 3;
  const int p = ((jj >> 4) << 3) | xcd;      // row tile [0,32)
  const int row0 = p * 64, col0 = (jj & 15) * 64;
  __shared__ __align__(16) short As[3 * 64 * 64];
  __shared__ __align__(16) short Bs[3 * 64 * 64];
  f32x4 acc[2][2];
  gemm_core_64x64(A, BT, row0, col0, As, Bs, acc);

  const int lane = threadIdx.x & 63, wv = threadIdx.x >> 6;
  const int lcol = lane & 15, quad = lane >> 4;
  const int wr = (wv >> 1) * 32, wc = (wv & 1) * 32;
  #pragma unroll
  for (int c = 0; c < 2; c++){
    const int cc = col0 + wc + c*16 + lcol;
    const float bb = bias[cc];
    #pragma unroll
    for (int r = 0; r < 2; r++)
      #pragma unroll
      for (int ri = 0; ri < 4; ri++){
        const int rr = row0 + wr + r*16 + quad*4 + ri;
        C[(size_t)rr * 1024 + cc] = acc[r][c][ri] + bb;
      }
  }
}

// ---------------- flash attention: one wave per 16-row q-group --------------
// R16 config exactly (the 183.5 us best). R20's cross-iteration pipeline +
// setprio REGRESSED (-3.7 us): avg span ~1.3 k-tiles, so the pipeline's
// register/VALU overhead is paid by every wave while its latency-hiding only
// helps the rare multi-tile waves. Reverted.
__global__ __launch_bounds__(64, 2) void attn_kernel(const short* __restrict__ qb,
                            const short* __restrict__ rbf,
                            const short* __restrict__ kk, const short* __restrict__ vT,
                            const int* __restrict__ ki,
                            const float* __restrict__ uk, const float* __restrict__ vr,
                            const int2* __restrict__ ranges,
                            short* __restrict__ attn_out){
  const int blk = blockIdx.x;
  const int xcd = blk & 7;
  const int idx = blk >> 3;                 // [0,256)
  const int bn  = (xcd << 2) | (idx >> 6);  // 4 (b,n) groups per XCD
  const int t16 = (idx & 63) * 16;
  const int n = bn & 15;
  const int b = bn >> 4;
  const int lane = threadIdx.x & 63;
  const int quad = lane >> 4, lcol = lane & 15;

  __shared__ __align__(16) short pb[16 * 72];

  const short* qp = qb + (size_t)(b * TT + t16 + lcol) * 1024 + n * 64 + quad * 8;
  bf16x8 aq0 = *(const bf16x8*)(qp);
  bf16x8 aq1 = *(const bf16x8*)(qp + 32);

  int trow[4], qi_r[4], sl[4];
  bool hi[4];
  #pragma unroll
  for (int r = 0; r < 4; r++){
    trow[r] = t16 + quad * 4 + r;
    qi_r[r] = ki[b * SS + MMEM + trow[r]];
    const int rt = quad * 4 + r;
    const int off = lcol + 15 - rt;
    sl[r] = quad * 16 + (off & 15);
    hi[r] = off >= 16;
  }

  float m_run[4], l_run[4];
  f32x4 o[4];
  #pragma unroll
  for (int r = 0; r < 4; r++){ m_run[r] = -1e30f; l_run[r] = 0.f; }
  #pragma unroll
  for (int c = 0; c < 4; c++) o[c] = (f32x4){0.f, 0.f, 0.f, 0.f};

  const float scale = 0.125f;
  const size_t vt_base = (size_t)((b * NHD + n) * HD);
  const short* rb_head = rbf + n * 64;
  const float* uk_row = uk + (size_t)(b * NHD + n) * SS;
  const float* vr_row = vr + (size_t)n * SS;

  const int2 rg = ranges[(b << 6) + (t16 >> 4)];
  const int kt0 = rg.x >> 6, kt1 = (rg.y - 1) >> 6;

  for (int kt = kt0; kt <= kt1; kt++){
    const int s0 = kt * 64;

    // ---- batched load phase 1: all K (8x bf16x8), all R (10x), scalars ----
    bf16x8 kb[4][2], rbr[5][2];
    float ukc[4], vrj[5];
    int ki_c[4];
    #pragma unroll
    for (int c = 0; c < 4; c++){
      const short* kp = kk + (size_t)(b * SS + s0 + 16 * c + lcol) * 1024 + n * 64 + quad * 8;
      kb[c][0] = *(const bf16x8*)(kp);
      kb[c][1] = *(const bf16x8*)(kp + 32);
      ukc[c] = uk_row[s0 + 16 * c + lcol];
      ki_c[c] = ki[b * SS + s0 + 16 * c + lcol];
    }
    const int j0 = s0 - t16 + 1008;   // >= 0 always
    #pragma unroll
    for (int c5 = 0; c5 < 5; c5++){
      int jr = j0 + 16 * c5 + lcol;
      jr = (jr > SS - 1) ? (SS - 1) : jr;   // clamped rows are causally masked
      const short* rp = rb_head + (size_t)jr * 1024 + quad * 8;
      rbr[c5][0] = *(const bf16x8*)(rp);
      rbr[c5][1] = *(const bf16x8*)(rp + 32);
      vrj[c5] = vr_row[jr];
    }

    // ---- S = Q . K^T ----
    f32x4 sacc[4];
    #pragma unroll
    for (int c = 0; c < 4; c++){
      f32x4 z = (f32x4){0.f, 0.f, 0.f, 0.f};
      z = __builtin_amdgcn_mfma_f32_16x16x32_bf16(aq0, kb[c][0], z, 0, 0, 0);
      z = __builtin_amdgcn_mfma_f32_16x16x32_bf16(aq1, kb[c][1], z, 0, 0, 0);
      sacc[c] = z;
    }
    // ---- D = Q . R^T (+ vr column bias) over the 80-row window ----
    f32x4 Dw[5];
    #pragma unroll
    for (int c5 = 0; c5 < 5; c5++){
      f32x4 z = (f32x4){0.f, 0.f, 0.f, 0.f};
      z = __builtin_amdgcn_mfma_f32_16x16x32_bf16(aq0, rbr[c5][0], z, 0, 0, 0);
      z = __builtin_amdgcn_mfma_f32_16x16x32_bf16(aq1, rbr[c5][1], z, 0, 0, 0);
      const float vv = vrj[c5];
      #pragma unroll
      for (int r = 0; r < 4; r++) z[r] += vv;
      Dw[c5] = z;
    }

    // ---- batched load phase 2: V (latency hides under shuffles/softmax) ----
    bf16x8 vb[4][2];
    #pragma unroll
    for (int c = 0; c < 4; c++){
      const short* vtp = vT + (vt_base + c * 16 + lcol) * (size_t)SS + s0 + quad * 8;
      vb[c][0] = *(const bf16x8*)(vtp);
      vb[c][1] = *(const bf16x8*)(vtp + 32);
    }

    // ---- bias shift (Toeplitz) + mask + logits ----
    float p[4][4];
    float rowmax[4];
    #pragma unroll
    for (int r = 0; r < 4; r++) rowmax[r] = -1e30f;
    #pragma unroll
    for (int c = 0; c < 4; c++){
      const int s = s0 + 16 * c + lcol;
      #pragma unroll
      for (int r = 0; r < 4; r++){
        const float v0 = __shfl(Dw[c][r], sl[r], 64);
        const float v1 = __shfl(Dw[c + 1][r], sl[r], 64);
        const float bd = hi[r] ? v1 : v0;
        float lg = (sacc[c][r] + ukc[c] + bd) * scale;
        const bool valid = (s <= trow[r] + MMEM) && (ki_c[c] == qi_r[r]);
        lg = valid ? lg : -1e30f;
        p[c][r] = lg;
        rowmax[r] = fmaxf(rowmax[r], lg);
      }
    }
    // ---- online softmax ----
    #pragma unroll
    for (int r = 0; r < 4; r++){
      float vmx = rowmax[r];
      #pragma unroll
      for (int off = 1; off < 16; off <<= 1) vmx = fmaxf(vmx, __shfl_xor(vmx, off, 64));
      float mnew = fmaxf(m_run[r], vmx);
      float alpha = __expf(m_run[r] - mnew);
      m_run[r] = mnew;
      l_run[r] *= alpha;
      #pragma unroll
      for (int c = 0; c < 4; c++) o[c][r] *= alpha;
    }
    float psum[4] = {0.f, 0.f, 0.f, 0.f};
    #pragma unroll
    for (int c = 0; c < 4; c++)
      #pragma unroll
      for (int r = 0; r < 4; r++){
        float pv = __expf(p[c][r] - m_run[r]);
        p[c][r] = pv;
        psum[r] += pv;
      }
    #pragma unroll
    for (int r = 0; r < 4; r++){
      float vs = psum[r];
      #pragma unroll
      for (int off = 1; off < 16; off <<= 1) vs += __shfl_xor(vs, off, 64);
      l_run[r] += vs;
    }
    // ---- P: C-layout -> A-layout via LDS (wave-synchronous) ----
    #pragma unroll
    for (int c = 0; c < 4; c++)
      #pragma unroll
      for (int r = 0; r < 4; r++)
        pb[(quad * 4 + r) * 72 + 16 * c + lcol] = f2bf(p[c][r]);
    bf16x8 pa0 = *(const bf16x8*)(&pb[lcol * 72 + quad * 8]);
    bf16x8 pa1 = *(const bf16x8*)(&pb[lcol * 72 + 32 + quad * 8]);
    // ---- O += P . V ----
    #pragma unroll
    for (int c = 0; c < 4; c++){
      o[c] = __builtin_amdgcn_mfma_f32_16x16x32_bf16(pa0, vb[c][0], o[c], 0, 0, 0);
      o[c] = __builtin_amdgcn_mfma_f32_16x16x32_bf16(pa1, vb[c][1], o[c], 0, 0, 0);
    }
  }

  // ---- epilogue: normalize, store bf16 attn [B*T, N*H] ----
  #pragma unroll
  for (int r = 0; r < 4; r++){
    const float inv = 1.f / l_run[r];
    const int t = trow[r];
    #pragma unroll
    for (int c = 0; c < 4; c++)
      attn_out[(size_t)(b * TT + t) * 1024 + n * 64 + c * 16 + lcol] = f2bf(o[c][r] * inv);
  }
}

// ---------------- launcher ----------------
extern "C" void kernel_launch(void* const* d_in, const int* in_sizes, int n_in,
                              void* d_out, int out_size, void* d_ws, size_t ws_size,
                              hipStream_t stream){
  const float* x      = (const float*)d_in[0];
  const float* rel    = (const float*)d_in[1];
  const float* memory = (const float*)d_in[2];
  const int*   episode_idx = (const int*)d_in[3];
  const int*   dones  = (const int*)d_in[4];
  const float* Wq  = (const float*)d_in[5];
  const float* Wk  = (const float*)d_in[6];
  const float* Wv  = (const float*)d_in[7];
  const float* Wr  = (const float*)d_in[8];
  const float* u   = (const float*)d_in[9];
  const float* v   = (const float*)d_in[10];
  const float* Wout  = (const float*)d_in[11];
  const float* b_out = (const float*)d_in[12];
  float* out = (float*)d_out;

  char* ws = (char*)d_ws;
  size_t off = 0;
  auto alloc = [&](size_t bytes) -> char* {
    char* p = ws + off;
    off += (bytes + 255) & ~(size_t)255;
    return p;
  };
  short* kv_bf  = (short*)alloc((size_t)NB * SS * FF * 2);
  short* rel_bf = (short*)alloc((size_t)SS * FF * 2);
  short* WqT    = (short*)alloc((size_t)FF * 1024 * 2);
  short* WkT    = (short*)alloc((size_t)FF * 1024 * 2);
  short* WvT    = (short*)alloc((size_t)FF * 1024 * 2);
  short* WrT    = (short*)alloc((size_t)FF * 1024 * 2);
  short* WoT    = (short*)alloc((size_t)FF * 1024 * 2);
  short* qbuf   = (short*)alloc((size_t)NB * TT * 1024 * 2);
  short* kbf    = (short*)alloc((size_t)NB * SS * 1024 * 2);
  short* vTb    = (short*)alloc((size_t)NB * SS * 1024 * 2);
  short* rbf    = (short*)alloc((size_t)SS * 1024 * 2);
  int*   ki     = (int*)  alloc((size_t)NB * SS * 4);
  int2*  ranges = (int2*) alloc((size_t)NB * 64 * 8);
  float* ukT    = (float*)alloc((size_t)NB * NHD * SS * 4);
  float* vrT    = (float*)alloc((size_t)NHD * SS * 4);
  short* attn   = (short*)alloc((size_t)NB * TT * 1024 * 2);
  (void)ws_size; (void)in_sizes; (void)n_in; (void)out_size;

  // merged prep: pack + 5x transpose-cast + scan (one launch, R15)
  prep_kernel<<<NKVB + NTRB + NB, 256, 0, stream>>>(
      memory, x, rel, episode_idx, dones,
      Wq, Wk, Wv, Wr, Wout,
      kv_bf, rel_bf, WqT, WkT, WvT, WrT, WoT, ki, ranges);

  // fused projections: z=0 dual-B K+V merge (R19), z=1 q, z=2 rbf
  proj_gemm<<<dim3(1024, 1, 3), 256, 0, stream>>>(kv_bf, rel_bf,
                                                  WkT, WvT, WqT, WrT,
                                                  kbf, vTb, qbuf, rbf, ranges);

  // u·k / v·r column-bias tables
  bias_tables<<<(NB*NHD*SS + NHD*SS + 255)/256, 256, 0, stream>>>(kbf, rbf, u, v, ukT, vrT);

  // attention: R16 config (measured best)
  attn_kernel<<<2048, 64, 0, stream>>>(qbuf, rbf, kbf, vTb, ki, ukT, vrT, ranges, attn);

  // output projection (XCD-locality swizzle, triple-buffer core)
  out_gemm<<<512, 256, 0, stream>>>(attn, WoT, b_out, out);
}